// Round 1
// baseline (487.508 us; speedup 1.0000x reference)
//
#include <hip/hip_runtime.h>

// 3x3 conv, stride 1, pad 1, NCHW, C=1. eff_w[i][j] = weight[i][j]*kx[i]*kx[j],
// kx = [den, 1, den]. x: (16,1,2048,2048) fp32 -> out same shape fp32.
//
// Memory-bound stencil. v2 changes vs v1 (103us kernel portion, ~5.9 TB/s eff):
//  - RPT 8 -> 32: vertical read amplification 10/8=1.25x -> 34/32=1.0625x
//    (saves ~50 MB of HBM fetch; traffic 604 -> 555 MB)
//  - bijective XCD swizzle (2048 blocks % 8 == 0): vertically-adjacent
//    rowgroups land on the same XCD so halo-row refetches can hit its L2
//  - non-temporal float4 stores: out is never re-read; keep L2/L3 for x

#define IMG_W 2048
#define IMG_H 2048
#define BATCH 16
#define RPT 32                      // rows per thread
#define WCHUNKS (IMG_W / 4)         // 512 float4 chunks per row
#define ROWGRPS (IMG_H / RPT)       // 64 row-groups per image
#define NTHREADS (WCHUNKS * ROWGRPS * BATCH)  // 524288
#define NBLOCKS (NTHREADS / 256)    // 2048
#define NXCD 8

typedef float f4 __attribute__((ext_vector_type(4)));

__global__ __launch_bounds__(256) void conv3x3_kernel(
    const float* __restrict__ x,
    const float* __restrict__ weight,
    const float* __restrict__ den,
    float* __restrict__ out)
{
    // XCD swizzle: HW round-robins blockIdx%8 across XCDs; remap so each XCD
    // owns a contiguous logical range (vertical halo L2 reuse). Bijective
    // since NBLOCKS % NXCD == 0.
    const int bid = (int)(blockIdx.x % NXCD) * (NBLOCKS / NXCD)
                  + (int)(blockIdx.x / NXCD);
    const int tid    = bid * 256 + (int)threadIdx.x;
    const int wchunk = tid & (WCHUNKS - 1);        // 9 bits
    const int rowgrp = (tid >> 9) & (ROWGRPS - 1); // 6 bits
    const int b      = tid >> 15;                  // 2^15 threads per image

    // effective 3x3 weights (scalar loads broadcast; cheap)
    const float d = den[0];
    const float k[3] = {d, 1.0f, d};
    float wgt[3][3];
#pragma unroll
    for (int i = 0; i < 3; ++i)
#pragma unroll
        for (int j = 0; j < 3; ++j)
            wgt[i][j] = weight[i * 3 + j] * k[i] * k[j];

    const float* xb = x   + (size_t)b * IMG_H * IMG_W;
    float*       ob = out + (size_t)b * IMG_H * IMG_W;
    const int w0 = wchunk * 4;
    const int h0 = rowgrp * RPT;
    const bool has_l = (w0 > 0);
    const bool has_r = (w0 + 4 < IMG_W);

    // row buffer layout: v[0]=col w0-1, v[1..4]=cols w0..w0+3, v[5]=col w0+4
    auto load_row = [&](int h, float v[6]) {
        if (h < 0 || h >= IMG_H) {   // wave-uniform branch (rowgrp uniform)
#pragma unroll
            for (int i = 0; i < 6; ++i) v[i] = 0.0f;
            return;
        }
        const float* r = xb + (size_t)h * IMG_W + w0;
        const f4 c = *(const f4*)r;
        v[1] = c.x; v[2] = c.y; v[3] = c.z; v[4] = c.w;
        v[0] = has_l ? r[-1] : 0.0f;  // L1/L2 hits (line fetched by neighbor)
        v[5] = has_r ? r[4]  : 0.0f;
    };

    float ra[6], rb[6], rc[6];
    load_row(h0 - 1, ra);  // h0==0 -> zeros (top padding)
    load_row(h0,     rb);

    // unroll 8 (not 32): full unroll invites aggressive load hoisting ->
    // VGPR blowup; 8 keeps rotation mostly register-renamed w/o spills
#pragma unroll 8
    for (int rr = 0; rr < RPT; ++rr) {
        load_row(h0 + rr + 1, rc);  // bottom padding handled inside

        f4 o;
#pragma unroll
        for (int j = 0; j < 4; ++j) {
            o[j] = wgt[0][0]*ra[j] + wgt[0][1]*ra[j+1] + wgt[0][2]*ra[j+2]
                 + wgt[1][0]*rb[j] + wgt[1][1]*rb[j+1] + wgt[1][2]*rb[j+2]
                 + wgt[2][0]*rc[j] + wgt[2][1]*rc[j+1] + wgt[2][2]*rc[j+2];
        }
        __builtin_nontemporal_store(
            o, (f4*)(ob + (size_t)(h0 + rr) * IMG_W + w0));

#pragma unroll
        for (int i = 0; i < 6; ++i) { ra[i] = rb[i]; rb[i] = rc[i]; }
    }
}

extern "C" void kernel_launch(void* const* d_in, const int* in_sizes, int n_in,
                              void* d_out, int out_size, void* d_ws, size_t ws_size,
                              hipStream_t stream) {
    const float* x      = (const float*)d_in[0];
    const float* weight = (const float*)d_in[1];
    const float* den    = (const float*)d_in[2];
    float*       out    = (float*)d_out;

    conv3x3_kernel<<<NBLOCKS, 256, 0, stream>>>(x, weight, den, out);
}

// Round 2
// 446.931 us; speedup vs baseline: 1.0908x; 1.0908x over previous
//
#include <hip/hip_runtime.h>

// 3x3 conv, stride 1, pad 1, NCHW, C=1. eff_w[i][j] = weight[i][j]*kx[i]*kx[j],
// kx = [den, 1, den]. x: (16,1,2048,2048) fp32 -> out same shape fp32.
//
// v3: latency-bound fix. v2 (RPT=32, unroll-8 + register rotation) compiled
// to VGPR=36 => compiler hoisted NOTHING, MLP=1 row/wave -> 191us latency-bound
// (VALUBusy 8%, 2.1 TB/s). v3 restores RPT=8 with an EXPLICIT preload of all
// 10 halo rows into registers before any compute: ~30 memory ops in flight
// per wave. Keeps NT stores (protect x's L3 residency; FETCH was 136MB thanks
// to L3) and the XCD swizzle (vertical halo neighbors land on same XCD L2).

#define IMG_W 2048
#define IMG_H 2048
#define BATCH 16
#define RPT 8                       // rows per thread
#define WCHUNKS (IMG_W / 4)         // 512 float4 chunks per row
#define ROWGRPS (IMG_H / RPT)       // 256 row-groups per image
#define NTHREADS (WCHUNKS * ROWGRPS * BATCH)  // 2,097,152
#define NBLOCKS (NTHREADS / 256)    // 8192
#define NXCD 8

typedef float f4 __attribute__((ext_vector_type(4)));

__global__ __launch_bounds__(256) void conv3x3_kernel(
    const float* __restrict__ x,
    const float* __restrict__ weight,
    const float* __restrict__ den,
    float* __restrict__ out)
{
    // XCD swizzle: bijective since NBLOCKS % NXCD == 0. Vertically-adjacent
    // rowgroups are +/-2 logical blocks -> same XCD chunk -> halo rows L2-hit.
    const int bid = (int)(blockIdx.x % NXCD) * (NBLOCKS / NXCD)
                  + (int)(blockIdx.x / NXCD);
    const int tid    = bid * 256 + (int)threadIdx.x;
    const int wchunk = tid & (WCHUNKS - 1);        // 9 bits
    const int rowgrp = (tid >> 9) & (ROWGRPS - 1); // 8 bits
    const int b      = tid >> 17;

    const float* xb = x   + (size_t)b * IMG_H * IMG_W;
    float*       ob = out + (size_t)b * IMG_H * IMG_W;
    const int w0 = wchunk * 4;
    const int h0 = rowgrp * RPT;
    const bool has_l = (w0 > 0);
    const bool has_r = (w0 + 4 < IMG_W);

    // row buffer layout: v[0]=col w0-1, v[1..4]=cols w0..w0+3, v[5]=col w0+4
    auto load_row = [&](int h, float v[6]) {
        if (h < 0 || h >= IMG_H) {   // wave-uniform (rowgrp uniform in wave)
#pragma unroll
            for (int i = 0; i < 6; ++i) v[i] = 0.0f;
            return;
        }
        const float* r = xb + (size_t)h * IMG_W + w0;
        const f4 c = *(const f4*)r;
        v[1] = c.x; v[2] = c.y; v[3] = c.z; v[4] = c.w;
        v[0] = has_l ? r[-1] : 0.0f;  // L1/L2 hit (line fetched by neighbor)
        v[5] = has_r ? r[4]  : 0.0f;
    };

    // ---- phase 1: issue ALL row loads (independent -> ~30 mem ops in flight)
    float r[RPT + 2][6];
#pragma unroll
    for (int i = 0; i < RPT + 2; ++i)
        load_row(h0 - 1 + i, r[i]);

    // effective 3x3 weights (scalar; computed while loads are in flight)
    const float d = den[0];
    const float k[3] = {d, 1.0f, d};
    float wgt[3][3];
#pragma unroll
    for (int i = 0; i < 3; ++i)
#pragma unroll
        for (int j = 0; j < 3; ++j)
            wgt[i][j] = weight[i * 3 + j] * k[i] * k[j];

    // ---- phase 2: compute + NT store (out never re-read; don't evict x's L3)
#pragma unroll
    for (int rr = 0; rr < RPT; ++rr) {
        f4 o;
#pragma unroll
        for (int j = 0; j < 4; ++j) {
            o[j] = wgt[0][0]*r[rr  ][j] + wgt[0][1]*r[rr  ][j+1] + wgt[0][2]*r[rr  ][j+2]
                 + wgt[1][0]*r[rr+1][j] + wgt[1][1]*r[rr+1][j+1] + wgt[1][2]*r[rr+1][j+2]
                 + wgt[2][0]*r[rr+2][j] + wgt[2][1]*r[rr+2][j+1] + wgt[2][2]*r[rr+2][j+2];
        }
        __builtin_nontemporal_store(
            o, (f4*)(ob + (size_t)(h0 + rr) * IMG_W + w0));
    }
}

extern "C" void kernel_launch(void* const* d_in, const int* in_sizes, int n_in,
                              void* d_out, int out_size, void* d_ws, size_t ws_size,
                              hipStream_t stream) {
    const float* x      = (const float*)d_in[0];
    const float* weight = (const float*)d_in[1];
    const float* den    = (const float*)d_in[2];
    float*       out    = (float*)d_out;

    conv3x3_kernel<<<NBLOCKS, 256, 0, stream>>>(x, weight, den, out);
}

// Round 3
// 435.131 us; speedup vs baseline: 1.1204x; 1.0271x over previous
//
#include <hip/hip_runtime.h>

// 3x3 conv, stride 1, pad 1, NCHW, C=1. eff_w[i][j] = weight[i][j]*kx[i]*kx[j],
// kx = [den, 1, den]. x: (16,1,2048,2048) fp32 -> out same shape fp32.
//
// v4 = measured-best v1 config (no NT stores, no XCD swizzle: both regressed
// ~12us in v3 -- x is L3-resident, swizzle costs ~2% there per m160) with:
//  - explicit preload of all 10 halo rows (guaranteed MLP; v2's VGPR=36
//    showed the compiler won't hoist on its own under partial unroll)
//  - shuffle-based horizontal halo: lane l-1's c.w IS col w0-1, lane l+1's
//    c.x IS col w0+4. 2 ds_bpermute per row replace 2 scalar loads;
//    VMEM instrs/wave drop 30 -> 12 (only lanes 0/63 keep masked edge loads).

#define IMG_W 2048
#define IMG_H 2048
#define BATCH 16
#define RPT 8                       // rows per thread
#define WCHUNKS (IMG_W / 4)         // 512 float4 chunks per row
#define ROWGRPS (IMG_H / RPT)       // 256 row-groups per image
#define NTHREADS (WCHUNKS * ROWGRPS * BATCH)  // 2,097,152
#define NBLOCKS (NTHREADS / 256)    // 8192

typedef float f4 __attribute__((ext_vector_type(4)));

__global__ __launch_bounds__(256) void conv3x3_kernel(
    const float* __restrict__ x,
    const float* __restrict__ weight,
    const float* __restrict__ den,
    float* __restrict__ out)
{
    const int tid    = (int)blockIdx.x * 256 + (int)threadIdx.x;
    const int lane   = (int)threadIdx.x & 63;
    const int wchunk = tid & (WCHUNKS - 1);        // 9 bits
    const int rowgrp = (tid >> 9) & (ROWGRPS - 1); // 8 bits
    const int b      = tid >> 17;

    const float* xb = x   + (size_t)b * IMG_H * IMG_W;
    float*       ob = out + (size_t)b * IMG_H * IMG_W;
    const int w0 = wchunk * 4;
    const int h0 = rowgrp * RPT;
    // wchunk==0 implies lane==0; wchunk==511 implies lane==63 (512 % 64 == 0),
    // so interior lanes ALWAYS have a valid in-wave neighbor for the halo.
    const bool has_l = (w0 > 0);
    const bool has_r = (w0 + 4 < IMG_W);

    // ---- phase 1: issue ALL row loads (independent; ~12 VMEM ops in flight
    // per wave: 10x dwordx4 + 2 exec-masked edge scalars per row for lanes
    // 0/63 only -- the instruction issues once per wave regardless)
    f4    c[RPT + 2];
    float le[RPT + 2], re[RPT + 2];
#pragma unroll
    for (int i = 0; i < RPT + 2; ++i) {
        const int h = h0 - 1 + i;
        le[i] = 0.0f; re[i] = 0.0f;
        if (h < 0 || h >= IMG_H) {   // wave-uniform (rowgrp uniform in wave)
            c[i] = (f4)0.0f;
            continue;
        }
        const float* r = xb + (size_t)h * IMG_W + w0;
        c[i] = *(const f4*)r;
        if (lane == 0  && has_l) le[i] = r[-1];
        if (lane == 63 && has_r) re[i] = r[4];
    }

    // effective 3x3 weights (scalar path; computed while loads are in flight)
    const float d = den[0];
    const float k[3] = {d, 1.0f, d};
    float wgt[3][3];
#pragma unroll
    for (int i = 0; i < 3; ++i)
#pragma unroll
        for (int j = 0; j < 3; ++j)
            wgt[i][j] = weight[i * 3 + j] * k[i] * k[j];

    // ---- phase 2: derive horizontal halo in-register via wave shuffles.
    // All lanes execute (wave-uniform control flow) -> shuffles well-defined.
    float v0[RPT + 2], v5[RPT + 2];
#pragma unroll
    for (int i = 0; i < RPT + 2; ++i) {
        const float ls = __shfl_up(c[i].w, 1);    // lane l <- lane l-1 col w0-1
        const float rs = __shfl_down(c[i].x, 1);  // lane l <- lane l+1 col w0+4
        v0[i] = (lane == 0)  ? le[i] : ls;
        v5[i] = (lane == 63) ? re[i] : rs;
    }

    // row element k (k=0..5 spanning cols w0-1 .. w0+4), constant k only:
#define EL(i, k) ((k) == 0 ? v0[i] : ((k) == 5 ? v5[i] : c[i][(k) - 1]))

    // ---- phase 3: compute + plain f4 store (v1 behavior)
#pragma unroll
    for (int rr = 0; rr < RPT; ++rr) {
        f4 o;
#pragma unroll
        for (int j = 0; j < 4; ++j) {
            o[j] = wgt[0][0]*EL(rr,   j) + wgt[0][1]*EL(rr,   j+1) + wgt[0][2]*EL(rr,   j+2)
                 + wgt[1][0]*EL(rr+1, j) + wgt[1][1]*EL(rr+1, j+1) + wgt[1][2]*EL(rr+1, j+2)
                 + wgt[2][0]*EL(rr+2, j) + wgt[2][1]*EL(rr+2, j+1) + wgt[2][2]*EL(rr+2, j+2);
        }
        *(f4*)(ob + (size_t)(h0 + rr) * IMG_W + w0) = o;
    }
#undef EL
}

extern "C" void kernel_launch(void* const* d_in, const int* in_sizes, int n_in,
                              void* d_out, int out_size, void* d_ws, size_t ws_size,
                              hipStream_t stream) {
    const float* x      = (const float*)d_in[0];
    const float* weight = (const float*)d_in[1];
    const float* den    = (const float*)d_in[2];
    float*       out    = (float*)d_out;

    conv3x3_kernel<<<NBLOCKS, 256, 0, stream>>>(x, weight, den, out);
}